// Round 5
// baseline (103.374 us; speedup 1.0000x reference)
//
#include <hip/hip_runtime.h>

// ExemplarNoAttention: logits[b,c] = log( sum_{e: label[e]==c} exp(-beta*d2[b,e]) + eps )
// d2[b,e] = ||x_b||^2 + ||e_e||^2 - 2<x_b,e_e>, clamped >= 0; beta = softplus(beta_raw).
//
// Round 14 = R13 resubmit (infra failure, no kernel verdict). From R12 = 94.7:
//   - CROWS 512 -> 256 (NCHUNK=196, NSTAGE=4): grid 4 x 196 = 784 blocks
//     (3.06/CU, the balance of the best-measured configs). Staging redundancy
//     stays 4x (R12's dedup kept). Bitwise-identical summation.
//   - bound-based subtile pre-skip: per-stage/wave ce-max (6 shfl + 6 fmax in
//     stage_write) + tb = fma(s2, max(d), cbl+cemax). RTE fma/add are monotone
//     => tb <= -25 implies every t <= -25 (exact skip; dead subtiles now cost
//     ~20 VALU ops instead of ~50). Inner exact skip kept for bound misses.
//   - dead-block traffic skip: block-wide vote on acc==0; dead blocks skip the
//     640-float part store; flags[btile][chunk] (ALWAYS written -> poison-safe)
//     lets reduce skip dead chunks' part reads. Skipped terms are exactly
//     +0.0f in unchanged k-order -> bitwise-identical output.
// Keeps: fused fp32 staging (norm+cvt in stage_write), labels-once-per-block,
// single barrier per stage, exp2 log-domain, contention-free partials.
// Harness floor (~42 us poison fill + restore dispatches) untouchable.

#define NB      1024
#define NE      50000
#define NCHUNK  196      // 196 chunks * 256 e-rows (last chunk padded in-kernel)
#define KD      64
#define NC      10
#define SROWS   64       // e-rows per stage
#define NSTAGE  4        // CROWS / SROWS
#define CROWS   256      // e-rows per chunk
#define LROW    72       // padded LDS row stride in halfs (144 B)
#define BCOLS   256      // batch cols per block (4 col-groups of 64 per wave-set)
#define NGRP    4        // col-groups per wave
#define NBT     (NB / BCOLS)  // 4 btiles

#define LOG2E   1.4426950408889634f

using half8   = __attribute__((ext_vector_type(8))) _Float16;  // 16x16x32 A/B frag (4 VGPRs)
using half4v  = __attribute__((ext_vector_type(4))) _Float16;  // 16x16x16 A/B frag (2 VGPRs)
using floatx4 = __attribute__((ext_vector_type(4))) float;

__device__ __forceinline__ float softplus_f(float x) {
  return (x > 20.f) ? x : log1pf(__expf(x));
}

__device__ __forceinline__ float exp2_hw(float x) {
#if __has_builtin(__builtin_amdgcn_exp2f)
  return __builtin_amdgcn_exp2f(x);
#else
  return exp2f(x);
#endif
}

// ---------------------------------------------------------------------------
// main: grid (4 btiles, 196 chunks), block = 4 waves, 256 batch cols per block.
// Wave w owns cols {btile*256 + w*16 + 64g : g=0..3}. Per stage (64 e-rows):
// prefetch next stage ex fp32 global->regs; compute 4 subtiles from LDS buf b
// (shared A-frags feed all 4 col-groups); cvt+norm prefetched rows -> buf b^1;
// ONE barrier.
// Subtile: 2 MFMA1 per group -> d_g[e][b]; bound tb = fma(s2, max_r d, cbl+cemax);
// if all lanes tb <= -25 -> skip everything (exact; monotone RTE). Else full
// t = min(fma(s2,d,cb+ce),0), exact inner skip, p = exp2(t) fp16, MFMA2 onehot.
// Flush: block liveness vote; dead blocks write only flags. Live blocks store
// their 640-float partial (coalesced, contention-free).
// ---------------------------------------------------------------------------
__global__ __launch_bounds__(256) void main_kernel(
    const float* __restrict__ x, const float* __restrict__ ex,
    const int* __restrict__ labels, const float* __restrict__ beta_raw,
    float* __restrict__ part, int* __restrict__ flags)
{
  __shared__ _Float16 Ah[2][SROWS * LROW];
  __shared__ float    Ce[2][SROWS];
  __shared__ float    CeMax[2][4];
  __shared__ int      Lb_all[CROWS];
  __shared__ int      blockLive;

  const int tid  = threadIdx.x;
  const int wave = tid >> 6;
  const int lane = tid & 63;
  const int l15  = lane & 15;
  const int quad = lane >> 4;

  const int btile = blockIdx.x;
  const int chunk = blockIdx.y;
  const int e0    = chunk * CROWS;
  const int bm0   = btile * BCOLS + wave * 16;  // col-group 0; group g at +64g

  const float beta = softplus_f(beta_raw[0]);
  const float nb2  = -beta * LOG2E;             // -beta*log2(e)
  const float s2   = 2.f * beta * LOG2E;

  // ---- labels for the whole chunk, once (covered by prologue barrier)
  {
    const int grow = e0 + tid;
    Lb_all[tid] = (grow < NE) ? labels[grow] : 0;
  }
  if (tid == 0) blockLive = 0;

  // ---- x B-frags + cb for 4 col-groups, from fp32 x, once per block ----
  half8 bx[NGRP][2];
  float cbl[NGRP];
  #pragma unroll
  for (int g = 0; g < NGRP; ++g) {
    const float* xr = x + (size_t)(bm0 + 64 * g + l15) * KD;
    const float4 v0 = *(const float4*)(xr + quad * 8);
    const float4 v1 = *(const float4*)(xr + quad * 8 + 4);
    const float4 v2 = *(const float4*)(xr + quad * 8 + 32);
    const float4 v3 = *(const float4*)(xr + quad * 8 + 36);
    bx[g][0] = half8{ (_Float16)v0.x, (_Float16)v0.y, (_Float16)v0.z, (_Float16)v0.w,
                      (_Float16)v1.x, (_Float16)v1.y, (_Float16)v1.z, (_Float16)v1.w };
    bx[g][1] = half8{ (_Float16)v2.x, (_Float16)v2.y, (_Float16)v2.z, (_Float16)v2.w,
                      (_Float16)v3.x, (_Float16)v3.y, (_Float16)v3.z, (_Float16)v3.w };
    float s = v0.x*v0.x + v0.y*v0.y + v0.z*v0.z + v0.w*v0.w
            + v1.x*v1.x + v1.y*v1.y + v1.z*v1.z + v1.w*v1.w
            + v2.x*v2.x + v2.y*v2.y + v2.z*v2.z + v2.w*v2.w
            + v3.x*v3.x + v3.y*v3.y + v3.z*v3.z + v3.w*v3.w;
    s += __shfl_xor(s, 16, 64);
    s += __shfl_xor(s, 32, 64);
    cbl[g] = nb2 * s;
  }

  // stage-load lane constants: thread t owns row (t>>2), fp32 cols [(t&3)*16..+16)
  const int srow = tid >> 2;
  const int scol = tid & 3;
  const int lofs = srow * LROW + scol * 16;

  float4 pf0, pf1, pf2, pf3;  // prefetched fp32 row slice
  bool   pvalid;

  auto stage_load = [&](int st) {
    const int grow = e0 + st * SROWS + srow;
    pvalid = grow < NE;
    pf0 = make_float4(0.f, 0.f, 0.f, 0.f);
    pf1 = pf0; pf2 = pf0; pf3 = pf0;
    if (pvalid) {
      const float* g = ex + (size_t)grow * KD + scol * 16;
      pf0 = *(const float4*)(g);
      pf1 = *(const float4*)(g + 4);
      pf2 = *(const float4*)(g + 8);
      pf3 = *(const float4*)(g + 12);
    }
  };

  auto stage_write = [&](int buf) {
    // norm: 16 squares + reduce across the 4 lanes sharing this row (scol)
    float sn = pf0.x*pf0.x + pf0.y*pf0.y + pf0.z*pf0.z + pf0.w*pf0.w
             + pf1.x*pf1.x + pf1.y*pf1.y + pf1.z*pf1.z + pf1.w*pf1.w
             + pf2.x*pf2.x + pf2.y*pf2.y + pf2.z*pf2.z + pf2.w*pf2.w
             + pf3.x*pf3.x + pf3.y*pf3.y + pf3.z*pf3.z + pf3.w*pf3.w;
    sn += __shfl_xor(sn, 1, 64);
    sn += __shfl_xor(sn, 2, 64);
    const float cev = pvalid ? (nb2 * sn) : -1e30f;
    const half8 h0 = { (_Float16)pf0.x, (_Float16)pf0.y, (_Float16)pf0.z, (_Float16)pf0.w,
                       (_Float16)pf1.x, (_Float16)pf1.y, (_Float16)pf1.z, (_Float16)pf1.w };
    const half8 h1 = { (_Float16)pf2.x, (_Float16)pf2.y, (_Float16)pf2.z, (_Float16)pf2.w,
                       (_Float16)pf3.x, (_Float16)pf3.y, (_Float16)pf3.z, (_Float16)pf3.w };
    *(half8*)(&Ah[buf][lofs])     = h0;
    *(half8*)(&Ah[buf][lofs + 8]) = h1;
    if (scol == 0) Ce[buf][srow] = cev;
    // per-wave ce-max (wave w wrote rows [16w,16w+16) == subtile w of this stage)
    float cv = (scol == 0) ? cev : -1e30f;
    cv = fmaxf(cv, __shfl_xor(cv, 1, 64));
    cv = fmaxf(cv, __shfl_xor(cv, 2, 64));
    cv = fmaxf(cv, __shfl_xor(cv, 4, 64));
    cv = fmaxf(cv, __shfl_xor(cv, 8, 64));
    cv = fmaxf(cv, __shfl_xor(cv, 16, 64));
    cv = fmaxf(cv, __shfl_xor(cv, 32, 64));
    if (lane == 0) CeMax[buf][wave] = cv;
  };

  // ---- prologue: stage 0 global -> regs -> LDS buf 0 ----
  stage_load(0);
  stage_write(0);
  __syncthreads();

  floatx4 acc[NGRP];
  #pragma unroll
  for (int g = 0; g < NGRP; ++g) acc[g] = floatx4{0.f, 0.f, 0.f, 0.f};

  for (int st = 0; st < NSTAGE; ++st) {
    const int b = st & 1;

    // prefetch next stage into registers (vmcnt chain, independent of ds_reads)
    if (st + 1 < NSTAGE) stage_load(st + 1);

    // compute 4 subtiles of 16 e-rows from LDS buf b
    #pragma unroll
    for (int sub = 0; sub < 4; ++sub) {
      const int abase = (sub * 16 + l15) * LROW + quad * 8;
      const half8 ae0 = *(const half8*)(&Ah[b][abase]);
      const half8 ae1 = *(const half8*)(&Ah[b][abase + 32]);

      floatx4 d[NGRP];
      #pragma unroll
      for (int g = 0; g < NGRP; ++g) {
        floatx4 t = {0.f, 0.f, 0.f, 0.f};
        t = __builtin_amdgcn_mfma_f32_16x16x32_f16(ae0, bx[g][0], t, 0, 0, 0);
        t = __builtin_amdgcn_mfma_f32_16x16x32_f16(ae1, bx[g][1], t, 0, 0, 0);
        d[g] = t;
      }

      // bound-based pre-skip: tb >= every t of this subtile (RTE fma/add are
      // monotone; cemax >= each ce). tb <= -25 for all lanes => exact no-op.
      const float cemax = CeMax[b][sub];
      float tbm = -1e30f;
      #pragma unroll
      for (int g = 0; g < NGRP; ++g) {
        const float dm = fmaxf(fmaxf(d[g][0], d[g][1]), fmaxf(d[g][2], d[g][3]));
        tbm = fmaxf(tbm, fmaf(s2, dm, cbl[g] + cemax));
      }
      if (__any(tbm > -25.f)) {
        const float4 ce4 = *(const float4*)(&Ce[b][sub * 16 + quad * 4]);
        const int4   lb4 = *(const int4*)(&Lb_all[st * SROWS + sub * 16 + quad * 4]);
        const float cef[4] = { ce4.x, ce4.y, ce4.z, ce4.w };

        float t[NGRP][4];
        #pragma unroll
        for (int g = 0; g < NGRP; ++g)
          #pragma unroll
          for (int r = 0; r < 4; ++r)
            t[g][r] = fminf(fmaf(s2, d[g][r], cbl[g] + cef[r]), 0.f);  // log2-domain

        // exact skip (bound may be conservative)
        float m = -1e30f;
        #pragma unroll
        for (int g = 0; g < NGRP; ++g)
          m = fmaxf(m, fmaxf(fmaxf(t[g][0], t[g][1]), fmaxf(t[g][2], t[g][3])));
        if (__any(m > -25.f)) {
          half4v oh;
          oh[0] = (lb4.x == l15) ? (_Float16)1.f : (_Float16)0.f;
          oh[1] = (lb4.y == l15) ? (_Float16)1.f : (_Float16)0.f;
          oh[2] = (lb4.z == l15) ? (_Float16)1.f : (_Float16)0.f;
          oh[3] = (lb4.w == l15) ? (_Float16)1.f : (_Float16)0.f;

          #pragma unroll
          for (int g = 0; g < NGRP; ++g) {
            half4v p;
            #pragma unroll
            for (int r = 0; r < 4; ++r) p[r] = (_Float16)exp2_hw(t[g][r]);
            acc[g] = __builtin_amdgcn_mfma_f32_16x16x16f16(oh, p, acc[g], 0, 0, 0);
          }
        }
      }
    }

    // single barrier per stage: writes go to buf b^1, whose last reads ended
    // before the barrier at the end of stage st-1; reads of buf b don't alias.
    if (st + 1 < NSTAGE) {
      stage_write((st + 1) & 1);
      __syncthreads();
    }
  }

  // ---- liveness vote + flush ----
  bool ll = false;
  #pragma unroll
  for (int g = 0; g < NGRP; ++g)
    #pragma unroll
    for (int r = 0; r < 4; ++r) ll |= (acc[g][r] != 0.f);
  __syncthreads();                    // all waves past last buf reads; blockLive=0 visible
  if (__any(ll) && lane == 0) blockLive = 1;
  __syncthreads();

  if (blockLive) {
    float* dst = part + (size_t)chunk * (NB * NC);
    #pragma unroll
    for (int r = 0; r < 4; ++r) {
      const int c = quad * 4 + r;
      if (c < NC) {
        #pragma unroll
        for (int g = 0; g < NGRP; ++g)
          dst[(bm0 + 64 * g + l15) * NC + c] = acc[g][r];
      }
    }
  }
  if (tid == 0) flags[btile * NCHUNK + chunk] = blockLive;
}

// ---------------------------------------------------------------------------
// reduce+finalize: out[bc] = log( sum_{k: flags[btile][k]} part[k][bc] + eps ).
// Skipped chunks contributed exactly +0.0f -> bitwise-identical sum, same
// k-order. Flag reads are block-uniform (btile uniform per reduce block);
// part reads coalesced when taken.
// ---------------------------------------------------------------------------
__global__ __launch_bounds__(256) void reduce_kernel(
    const float* __restrict__ part, const int* __restrict__ flags,
    float* __restrict__ out)
{
  const int bc = blockIdx.x * 256 + threadIdx.x;
  if (bc < NB * NC) {
    const int btile = bc / (BCOLS * NC);
    const int fbase = btile * NCHUNK;
    float s = 0.f;
    for (int k = 0; k < NCHUNK; ++k) {
      if (flags[fbase + k]) s += part[(size_t)k * (NB * NC) + bc];
    }
    out[bc] = __logf(s + 1e-12f);
  }
}

extern "C" void kernel_launch(void* const* d_in, const int* in_sizes, int n_in,
                              void* d_out, int out_size, void* d_ws, size_t ws_size,
                              hipStream_t stream)
{
  const float* x        = (const float*)d_in[0];
  const float* ex       = (const float*)d_in[1];
  const int*   labels   = (const int*)d_in[2];
  const float* beta_raw = (const float*)d_in[3];
  float* out = (float*)d_out;

  // Workspace: part 196*10240*4 = 8,028,160 B; flags 4*196*4 = 3,136 B
  char* ws = (char*)d_ws;
  float* part  = (float*)ws;
  int*   flags = (int*)(ws + (size_t)NCHUNK * NB * NC * 4);

  dim3 g(NBT, NCHUNK);
  main_kernel<<<g, 256, 0, stream>>>(x, ex, labels, beta_raw, part, flags);
  reduce_kernel<<<40, 256, 0, stream>>>(part, flags, out);
}

// Round 7
// 97.925 us; speedup vs baseline: 1.0556x; 1.0556x over previous
//
#include <hip/hip_runtime.h>

// ExemplarNoAttention: logits[b,c] = log( sum_{e: label[e]==c} exp(-beta*d2[b,e]) + eps )
// d2[b,e] = ||x_b||^2 + ||e_e||^2 - 2<x_b,e_e>, clamped >= 0; beta = softplus(beta_raw).
//
// Round 16 (from R15 FAILED cooperative fusion; best passing = R11 = 94.5 us):
//  R15 post-mortem: 784 blocks exceed cooperative co-residency (~768 max at
//  this LDS/VGPR footprint) -> grid.sync() launch failed -> out never written
//  (absmax == |log(eps)|). Cooperative line abandoned. Also corrected ladder
//  read: R10->R11 (prep-dispatch removal) saved only 0.5 us -> dispatch-gap
//  overhead is ~1 us, not 4-5 -> fusion upside was misestimated.
//  R16 = R11 core VERBATIM (BCOLS=128, NSTAGE=8, single barrier per stage,
//  exp2 log-domain, exact dead-subtile skip) + the two provably-safe traffic
//  eliminations whose correctness was demonstrated in R14:
//   - dead-block store skip: block-wide vote on acc==0; dead blocks skip the
//     640-float part store (saves ~4 MB of writes; on this data ~all blocks).
//   - flags[btile][chunk] ALWAYS written (poison-safe) -> reduce skips dead
//     chunks' part reads (saves ~4 MB of reads). Skipped terms are exactly
//     +0.0f in unchanged k-order -> bitwise-identical output.
// Harness floor (~42 us poison fill + restore dispatches) untouchable.

#define NB      1024
#define NE      50000
#define NCHUNK  98       // 98 chunks * 512 e-rows (padded in-kernel)
#define KD      64
#define NC      10
#define SROWS   64       // e-rows per stage
#define NSTAGE  8        // CROWS / SROWS
#define CROWS   512      // e-rows per chunk
#define LROW    72       // padded LDS row stride in halfs (144 B)
#define BCOLS   128      // batch cols per block (2 col-groups of 64 per wave-set)
#define NBT     (NB / BCOLS)  // 8 btiles

#define LOG2E   1.4426950408889634f

using half8   = __attribute__((ext_vector_type(8))) _Float16;  // 16x16x32 A/B frag (4 VGPRs)
using half4v  = __attribute__((ext_vector_type(4))) _Float16;  // 16x16x16 A/B frag (2 VGPRs)
using floatx4 = __attribute__((ext_vector_type(4))) float;

__device__ __forceinline__ float softplus_f(float x) {
  return (x > 20.f) ? x : log1pf(__expf(x));
}

__device__ __forceinline__ float exp2_hw(float x) {
#if __has_builtin(__builtin_amdgcn_exp2f)
  return __builtin_amdgcn_exp2f(x);
#else
  return exp2f(x);
#endif
}

// ---------------------------------------------------------------------------
// main: grid (8 btiles, 98 chunks), block = 4 waves, 128 batch cols per block.
// Wave w owns cols {btile*128 + w*16, +64}. Per stage (64 e-rows): prefetch
// next stage ex fp32 global->regs; compute 4 subtiles from LDS buf b; cvt+norm
// prefetched rows -> buf b^1; ONE barrier.
// Subtile: MFMA1 16x16x32 x4 -> d[e][b]; t = min(fma(s2,d,cb+ce),0) log2-dom;
// exact skip if all t <= -25 (fp16(2^t)==0, RTE); else p=exp2(t), MFMA2 onehot.
// Flush: liveness vote; live blocks store 640-float partial; flags always.
// ---------------------------------------------------------------------------
__global__ __launch_bounds__(256) void main_kernel(
    const float* __restrict__ x, const float* __restrict__ ex,
    const int* __restrict__ labels, const float* __restrict__ beta_raw,
    float* __restrict__ part, int* __restrict__ flags)
{
  __shared__ _Float16 Ah[2][SROWS * LROW];
  __shared__ float    Ce[2][SROWS];
  __shared__ int      Lb_all[CROWS];
  __shared__ int      blockLive;

  const int tid  = threadIdx.x;
  const int wave = tid >> 6;
  const int lane = tid & 63;
  const int l15  = lane & 15;
  const int quad = lane >> 4;

  const int btile = blockIdx.x;
  const int chunk = blockIdx.y;
  const int e0    = chunk * CROWS;
  const int bm0   = btile * BCOLS + wave * 16;  // col-group 0
  const int bm1   = bm0 + 64;                   // col-group 1

  const float beta = softplus_f(beta_raw[0]);
  const float nb2  = -beta * LOG2E;             // -beta*log2(e)
  const float s2   = 2.f * beta * LOG2E;

  // ---- labels for the whole chunk, once (covered by prologue barrier)
  #pragma unroll
  for (int i = 0; i < CROWS / 256; ++i) {
    const int r = i * 256 + tid;
    const int grow = e0 + r;
    Lb_all[r] = (grow < NE) ? labels[grow] : 0;
  }
  if (tid == 0) blockLive = 0;

  // ---- x B-frags + cb for both col-groups, from fp32 x, once per block ----
  const float* xr0 = x + (size_t)(bm0 + l15) * KD;
  const float* xr1 = x + (size_t)(bm1 + l15) * KD;
  const float4 xa0 = *(const float4*)(xr0 + quad * 8);
  const float4 xa1 = *(const float4*)(xr0 + quad * 8 + 4);
  const float4 xa2 = *(const float4*)(xr0 + quad * 8 + 32);
  const float4 xa3 = *(const float4*)(xr0 + quad * 8 + 36);
  const float4 xb0 = *(const float4*)(xr1 + quad * 8);
  const float4 xb1 = *(const float4*)(xr1 + quad * 8 + 4);
  const float4 xb2 = *(const float4*)(xr1 + quad * 8 + 32);
  const float4 xb3 = *(const float4*)(xr1 + quad * 8 + 36);

  const half8 bx00 = { (_Float16)xa0.x, (_Float16)xa0.y, (_Float16)xa0.z, (_Float16)xa0.w,
                       (_Float16)xa1.x, (_Float16)xa1.y, (_Float16)xa1.z, (_Float16)xa1.w };
  const half8 bx01 = { (_Float16)xa2.x, (_Float16)xa2.y, (_Float16)xa2.z, (_Float16)xa2.w,
                       (_Float16)xa3.x, (_Float16)xa3.y, (_Float16)xa3.z, (_Float16)xa3.w };
  const half8 bx10 = { (_Float16)xb0.x, (_Float16)xb0.y, (_Float16)xb0.z, (_Float16)xb0.w,
                       (_Float16)xb1.x, (_Float16)xb1.y, (_Float16)xb1.z, (_Float16)xb1.w };
  const half8 bx11 = { (_Float16)xb2.x, (_Float16)xb2.y, (_Float16)xb2.z, (_Float16)xb2.w,
                       (_Float16)xb3.x, (_Float16)xb3.y, (_Float16)xb3.z, (_Float16)xb3.w };

  float sx0 = xa0.x*xa0.x + xa0.y*xa0.y + xa0.z*xa0.z + xa0.w*xa0.w
            + xa1.x*xa1.x + xa1.y*xa1.y + xa1.z*xa1.z + xa1.w*xa1.w
            + xa2.x*xa2.x + xa2.y*xa2.y + xa2.z*xa2.z + xa2.w*xa2.w
            + xa3.x*xa3.x + xa3.y*xa3.y + xa3.z*xa3.z + xa3.w*xa3.w;
  float sx1 = xb0.x*xb0.x + xb0.y*xb0.y + xb0.z*xb0.z + xb0.w*xb0.w
            + xb1.x*xb1.x + xb1.y*xb1.y + xb1.z*xb1.z + xb1.w*xb1.w
            + xb2.x*xb2.x + xb2.y*xb2.y + xb2.z*xb2.z + xb2.w*xb2.w
            + xb3.x*xb3.x + xb3.y*xb3.y + xb3.z*xb3.z + xb3.w*xb3.w;
  sx0 += __shfl_xor(sx0, 16, 64);  sx0 += __shfl_xor(sx0, 32, 64);
  sx1 += __shfl_xor(sx1, 16, 64);  sx1 += __shfl_xor(sx1, 32, 64);
  const float cb0l = nb2 * sx0;
  const float cb1l = nb2 * sx1;

  // stage-load lane constants: thread t owns row (t>>2), fp32 cols [(t&3)*16..+16)
  const int srow = tid >> 2;
  const int scol = tid & 3;
  const int lofs = srow * LROW + scol * 16;

  float4 pf0, pf1, pf2, pf3;  // prefetched fp32 row slice
  bool   pvalid;

  auto stage_load = [&](int st) {
    const int grow = e0 + st * SROWS + srow;
    pvalid = grow < NE;
    pf0 = make_float4(0.f, 0.f, 0.f, 0.f);
    pf1 = pf0; pf2 = pf0; pf3 = pf0;
    if (pvalid) {
      const float* g = ex + (size_t)grow * KD + scol * 16;
      pf0 = *(const float4*)(g);
      pf1 = *(const float4*)(g + 4);
      pf2 = *(const float4*)(g + 8);
      pf3 = *(const float4*)(g + 12);
    }
  };

  auto stage_write = [&](int buf) {
    float sn = pf0.x*pf0.x + pf0.y*pf0.y + pf0.z*pf0.z + pf0.w*pf0.w
             + pf1.x*pf1.x + pf1.y*pf1.y + pf1.z*pf1.z + pf1.w*pf1.w
             + pf2.x*pf2.x + pf2.y*pf2.y + pf2.z*pf2.z + pf2.w*pf2.w
             + pf3.x*pf3.x + pf3.y*pf3.y + pf3.z*pf3.z + pf3.w*pf3.w;
    sn += __shfl_xor(sn, 1, 64);
    sn += __shfl_xor(sn, 2, 64);
    const half8 h0 = { (_Float16)pf0.x, (_Float16)pf0.y, (_Float16)pf0.z, (_Float16)pf0.w,
                       (_Float16)pf1.x, (_Float16)pf1.y, (_Float16)pf1.z, (_Float16)pf1.w };
    const half8 h1 = { (_Float16)pf2.x, (_Float16)pf2.y, (_Float16)pf2.z, (_Float16)pf2.w,
                       (_Float16)pf3.x, (_Float16)pf3.y, (_Float16)pf3.z, (_Float16)pf3.w };
    *(half8*)(&Ah[buf][lofs])     = h0;
    *(half8*)(&Ah[buf][lofs + 8]) = h1;
    if (scol == 0) Ce[buf][srow] = pvalid ? (nb2 * sn) : -1e30f;
  };

  // ---- prologue: stage 0 global -> regs -> LDS buf 0 ----
  stage_load(0);
  stage_write(0);
  __syncthreads();

  floatx4 acc0 = {0.f, 0.f, 0.f, 0.f};
  floatx4 acc1 = {0.f, 0.f, 0.f, 0.f};

  for (int st = 0; st < NSTAGE; ++st) {
    const int b = st & 1;

    if (st + 1 < NSTAGE) stage_load(st + 1);

    #pragma unroll
    for (int sub = 0; sub < 4; ++sub) {
      const int abase = (sub * 16 + l15) * LROW + quad * 8;
      const half8 ae0 = *(const half8*)(&Ah[b][abase]);
      const half8 ae1 = *(const half8*)(&Ah[b][abase + 32]);
      const float4 ce4 = *(const float4*)(&Ce[b][sub * 16 + quad * 4]);
      const int4   lb4 = *(const int4*)(&Lb_all[st * SROWS + sub * 16 + quad * 4]);

      floatx4 d0 = {0.f, 0.f, 0.f, 0.f};
      floatx4 d1 = {0.f, 0.f, 0.f, 0.f};
      d0 = __builtin_amdgcn_mfma_f32_16x16x32_f16(ae0, bx00, d0, 0, 0, 0);
      d0 = __builtin_amdgcn_mfma_f32_16x16x32_f16(ae1, bx01, d0, 0, 0, 0);
      d1 = __builtin_amdgcn_mfma_f32_16x16x32_f16(ae0, bx10, d1, 0, 0, 0);
      d1 = __builtin_amdgcn_mfma_f32_16x16x32_f16(ae1, bx11, d1, 0, 0, 0);

      const float cef[4] = { ce4.x, ce4.y, ce4.z, ce4.w };
      float t0[4], t1[4];
      #pragma unroll
      for (int r = 0; r < 4; ++r) {
        t0[r] = fminf(fmaf(s2, d0[r], cb0l + cef[r]), 0.f);  // log2-domain
        t1[r] = fminf(fmaf(s2, d1[r], cb1l + cef[r]), 0.f);
      }

      // dead-subtile skip: t <= -25 => fp16(2^t) == 0 exactly (RTE) => MFMA2
      // is a provable no-op. Wave-uniform branch.
      const float m0 = fmaxf(fmaxf(t0[0], t0[1]), fmaxf(t0[2], t0[3]));
      const float m1 = fmaxf(fmaxf(t1[0], t1[1]), fmaxf(t1[2], t1[3]));
      if (__any(fmaxf(m0, m1) > -25.f)) {
        half4v oh;
        oh[0] = (lb4.x == l15) ? (_Float16)1.f : (_Float16)0.f;
        oh[1] = (lb4.y == l15) ? (_Float16)1.f : (_Float16)0.f;
        oh[2] = (lb4.z == l15) ? (_Float16)1.f : (_Float16)0.f;
        oh[3] = (lb4.w == l15) ? (_Float16)1.f : (_Float16)0.f;

        half4v p0, p1;
        #pragma unroll
        for (int r = 0; r < 4; ++r) {
          p0[r] = (_Float16)exp2_hw(t0[r]);
          p1[r] = (_Float16)exp2_hw(t1[r]);
        }

        acc0 = __builtin_amdgcn_mfma_f32_16x16x16f16(oh, p0, acc0, 0, 0, 0);
        acc1 = __builtin_amdgcn_mfma_f32_16x16x16f16(oh, p1, acc1, 0, 0, 0);
      }
    }

    if (st + 1 < NSTAGE) {
      stage_write((st + 1) & 1);
      __syncthreads();
    }
  }

  // ---- liveness vote + flush (dead blocks skip the part store) ----
  bool ll = false;
  #pragma unroll
  for (int r = 0; r < 4; ++r) ll |= (acc0[r] != 0.f) | (acc1[r] != 0.f);
  __syncthreads();                    // all waves done with LDS; blockLive=0 visible
  if (__any(ll) && lane == 0) blockLive = 1;
  __syncthreads();

  if (blockLive) {
    float* dst = part + (size_t)chunk * (NB * NC);
    #pragma unroll
    for (int r = 0; r < 4; ++r) {
      const int c = quad * 4 + r;
      if (c < NC) {
        dst[(bm0 + l15) * NC + c] = acc0[r];
        dst[(bm1 + l15) * NC + c] = acc1[r];
      }
    }
  }
  if (tid == 0) flags[btile * NCHUNK + chunk] = blockLive;
}

// ---------------------------------------------------------------------------
// reduce+finalize: out[bc] = log( sum_{k: flags[btile][k]} part[k][bc] + eps ).
// Skipped chunks contributed exactly +0.0f -> bitwise-identical sum, same
// k-order. Flag reads are block-uniform per rbtile; part reads coalesced.
// ---------------------------------------------------------------------------
__global__ __launch_bounds__(256) void reduce_kernel(
    const float* __restrict__ part, const int* __restrict__ flags,
    float* __restrict__ out)
{
  const int bc = blockIdx.x * 256 + threadIdx.x;
  if (bc < NB * NC) {
    const int rbtile = bc / (BCOLS * NC);
    const int fbase  = rbtile * NCHUNK;
    float s = 0.f;
    for (int k = 0; k < NCHUNK; ++k) {
      if (flags[fbase + k]) s += part[(size_t)k * (NB * NC) + bc];
    }
    out[bc] = __logf(s + 1e-12f);
  }
}

extern "C" void kernel_launch(void* const* d_in, const int* in_sizes, int n_in,
                              void* d_out, int out_size, void* d_ws, size_t ws_size,
                              hipStream_t stream)
{
  const float* x        = (const float*)d_in[0];
  const float* ex       = (const float*)d_in[1];
  const int*   labels   = (const int*)d_in[2];
  const float* beta_raw = (const float*)d_in[3];
  float* out = (float*)d_out;

  // Workspace: part 98*10240*4 = 4,014,080 B; flags 8*98*4 = 3,136 B
  char* ws = (char*)d_ws;
  float* part  = (float*)ws;
  int*   flags = (int*)(ws + (size_t)NCHUNK * NB * NC * 4);

  dim3 g(NBT, NCHUNK);
  main_kernel<<<g, 256, 0, stream>>>(x, ex, labels, beta_raw, part, flags);
  reduce_kernel<<<40, 256, 0, stream>>>(part, flags, out);
}

// Round 8
// 95.862 us; speedup vs baseline: 1.0784x; 1.0215x over previous
//
#include <hip/hip_runtime.h>

// ExemplarNoAttention: logits[b,c] = log( sum_{e: label[e]==c} exp(-beta*d2[b,e]) + eps )
// d2[b,e] = ||x_b||^2 + ||e_e||^2 - 2<x_b,e_e>, clamped >= 0; beta = softplus(beta_raw).
//
// Round 17 = R11 VERBATIM REVERT (best passing, 94.47 us).
//  Ladder: R10=94.97, R11=94.47, R12=94.65, R14=103.4 (CROWS/bound-skip
//  restructure, regressed), R15 failed (cooperative co-residency), R16=97.9
//  (liveness-vote + flags: 2 extra tail barriers + flag-gated reduce cost more
//  than the ~5 us of never-critical coalesced partial stores they saved).
//  Conclusion: every add-on beyond this core measured neutral-to-negative.
//  Structure: single fused main (fp32 staging + norm/cvt folded into the LDS
//  write phase, x B-frags + cb once per block), 128 batch cols/block, 8-stage
//  double-buffered K-loop with ONE barrier per stage, exp2 log-domain with
//  exact dead-subtile skip (t<=-25 => fp16(2^t)==0 under RTE => MFMA2 no-op),
//  contention-free per-chunk partial stores, coalesced flag-free reduce.
//  Remaining time is harness floor: 268 MB poison fill (~42 us @ ~80% HBM
//  peak), input restores, 2 dispatch overheads, ~9 us compute.

#define NB      1024
#define NE      50000
#define NCHUNK  98       // 98 chunks * 512 e-rows (padded in-kernel)
#define KD      64
#define NC      10
#define SROWS   64       // e-rows per stage
#define NSTAGE  8        // CROWS / SROWS
#define CROWS   512      // e-rows per chunk
#define LROW    72       // padded LDS row stride in halfs (144 B)
#define BCOLS   128      // batch cols per block (2 col-groups of 64 per wave-set)

#define LOG2E   1.4426950408889634f

using half8   = __attribute__((ext_vector_type(8))) _Float16;  // 16x16x32 A/B frag (4 VGPRs)
using half4v  = __attribute__((ext_vector_type(4))) _Float16;  // 16x16x16 A/B frag (2 VGPRs)
using floatx4 = __attribute__((ext_vector_type(4))) float;

__device__ __forceinline__ float softplus_f(float x) {
  return (x > 20.f) ? x : log1pf(__expf(x));
}

__device__ __forceinline__ float exp2_hw(float x) {
#if __has_builtin(__builtin_amdgcn_exp2f)
  return __builtin_amdgcn_exp2f(x);
#else
  return exp2f(x);
#endif
}

// ---------------------------------------------------------------------------
// main: grid (8 btiles, 98 chunks), block = 4 waves, 128 batch cols per block.
// Wave w owns cols {btile*128 + w*16, +64}. Per stage (64 e-rows): prefetch
// next stage ex fp32 global->regs; compute 4 subtiles from LDS buf b; cvt+norm
// prefetched rows -> buf b^1; ONE barrier.
// Subtile: MFMA1 16x16x32 x4 -> d[e][b]; t = min(fma(s2,d,cb+ce),0) log2-dom;
// exact skip if all t <= -25 (fp16(2^t)==0, RTE); else p=exp2(t), MFMA2 onehot.
// Flush: plain coalesced stores into part[chunk] -- zero atomics/contention.
// ---------------------------------------------------------------------------
__global__ __launch_bounds__(256) void main_kernel(
    const float* __restrict__ x, const float* __restrict__ ex,
    const int* __restrict__ labels, const float* __restrict__ beta_raw,
    float* __restrict__ part)
{
  __shared__ _Float16 Ah[2][SROWS * LROW];
  __shared__ float    Ce[2][SROWS];
  __shared__ int      Lb_all[CROWS];

  const int tid  = threadIdx.x;
  const int wave = tid >> 6;
  const int lane = tid & 63;
  const int l15  = lane & 15;
  const int quad = lane >> 4;

  const int btile = blockIdx.x;
  const int chunk = blockIdx.y;
  const int e0    = chunk * CROWS;
  const int bm0   = btile * BCOLS + wave * 16;  // col-group 0
  const int bm1   = bm0 + 64;                   // col-group 1

  const float beta = softplus_f(beta_raw[0]);
  const float nb2  = -beta * LOG2E;             // -beta*log2(e)
  const float s2   = 2.f * beta * LOG2E;

  // ---- labels for the whole chunk, once (covered by prologue barrier)
  #pragma unroll
  for (int i = 0; i < CROWS / 256; ++i) {
    const int r = i * 256 + tid;
    const int grow = e0 + r;
    Lb_all[r] = (grow < NE) ? labels[grow] : 0;
  }

  // ---- x B-frags + cb for both col-groups, from fp32 x, once per block ----
  const float* xr0 = x + (size_t)(bm0 + l15) * KD;
  const float* xr1 = x + (size_t)(bm1 + l15) * KD;
  const float4 xa0 = *(const float4*)(xr0 + quad * 8);
  const float4 xa1 = *(const float4*)(xr0 + quad * 8 + 4);
  const float4 xa2 = *(const float4*)(xr0 + quad * 8 + 32);
  const float4 xa3 = *(const float4*)(xr0 + quad * 8 + 36);
  const float4 xb0 = *(const float4*)(xr1 + quad * 8);
  const float4 xb1 = *(const float4*)(xr1 + quad * 8 + 4);
  const float4 xb2 = *(const float4*)(xr1 + quad * 8 + 32);
  const float4 xb3 = *(const float4*)(xr1 + quad * 8 + 36);

  const half8 bx00 = { (_Float16)xa0.x, (_Float16)xa0.y, (_Float16)xa0.z, (_Float16)xa0.w,
                       (_Float16)xa1.x, (_Float16)xa1.y, (_Float16)xa1.z, (_Float16)xa1.w };
  const half8 bx01 = { (_Float16)xa2.x, (_Float16)xa2.y, (_Float16)xa2.z, (_Float16)xa2.w,
                       (_Float16)xa3.x, (_Float16)xa3.y, (_Float16)xa3.z, (_Float16)xa3.w };
  const half8 bx10 = { (_Float16)xb0.x, (_Float16)xb0.y, (_Float16)xb0.z, (_Float16)xb0.w,
                       (_Float16)xb1.x, (_Float16)xb1.y, (_Float16)xb1.z, (_Float16)xb1.w };
  const half8 bx11 = { (_Float16)xb2.x, (_Float16)xb2.y, (_Float16)xb2.z, (_Float16)xb2.w,
                       (_Float16)xb3.x, (_Float16)xb3.y, (_Float16)xb3.z, (_Float16)xb3.w };

  float sx0 = xa0.x*xa0.x + xa0.y*xa0.y + xa0.z*xa0.z + xa0.w*xa0.w
            + xa1.x*xa1.x + xa1.y*xa1.y + xa1.z*xa1.z + xa1.w*xa1.w
            + xa2.x*xa2.x + xa2.y*xa2.y + xa2.z*xa2.z + xa2.w*xa2.w
            + xa3.x*xa3.x + xa3.y*xa3.y + xa3.z*xa3.z + xa3.w*xa3.w;
  float sx1 = xb0.x*xb0.x + xb0.y*xb0.y + xb0.z*xb0.z + xb0.w*xb0.w
            + xb1.x*xb1.x + xb1.y*xb1.y + xb1.z*xb1.z + xb1.w*xb1.w
            + xb2.x*xb2.x + xb2.y*xb2.y + xb2.z*xb2.z + xb2.w*xb2.w
            + xb3.x*xb3.x + xb3.y*xb3.y + xb3.z*xb3.z + xb3.w*xb3.w;
  sx0 += __shfl_xor(sx0, 16, 64);  sx0 += __shfl_xor(sx0, 32, 64);
  sx1 += __shfl_xor(sx1, 16, 64);  sx1 += __shfl_xor(sx1, 32, 64);
  const float cb0l = nb2 * sx0;
  const float cb1l = nb2 * sx1;

  // stage-load lane constants: thread t owns row (t>>2), fp32 cols [(t&3)*16..+16)
  const int srow = tid >> 2;
  const int scol = tid & 3;
  const int lofs = srow * LROW + scol * 16;

  float4 pf0, pf1, pf2, pf3;  // prefetched fp32 row slice
  bool   pvalid;

  auto stage_load = [&](int st) {
    const int grow = e0 + st * SROWS + srow;
    pvalid = grow < NE;
    pf0 = make_float4(0.f, 0.f, 0.f, 0.f);
    pf1 = pf0; pf2 = pf0; pf3 = pf0;
    if (pvalid) {
      const float* g = ex + (size_t)grow * KD + scol * 16;
      pf0 = *(const float4*)(g);
      pf1 = *(const float4*)(g + 4);
      pf2 = *(const float4*)(g + 8);
      pf3 = *(const float4*)(g + 12);
    }
  };

  auto stage_write = [&](int buf) {
    float sn = pf0.x*pf0.x + pf0.y*pf0.y + pf0.z*pf0.z + pf0.w*pf0.w
             + pf1.x*pf1.x + pf1.y*pf1.y + pf1.z*pf1.z + pf1.w*pf1.w
             + pf2.x*pf2.x + pf2.y*pf2.y + pf2.z*pf2.z + pf2.w*pf2.w
             + pf3.x*pf3.x + pf3.y*pf3.y + pf3.z*pf3.z + pf3.w*pf3.w;
    sn += __shfl_xor(sn, 1, 64);
    sn += __shfl_xor(sn, 2, 64);
    const half8 h0 = { (_Float16)pf0.x, (_Float16)pf0.y, (_Float16)pf0.z, (_Float16)pf0.w,
                       (_Float16)pf1.x, (_Float16)pf1.y, (_Float16)pf1.z, (_Float16)pf1.w };
    const half8 h1 = { (_Float16)pf2.x, (_Float16)pf2.y, (_Float16)pf2.z, (_Float16)pf2.w,
                       (_Float16)pf3.x, (_Float16)pf3.y, (_Float16)pf3.z, (_Float16)pf3.w };
    *(half8*)(&Ah[buf][lofs])     = h0;
    *(half8*)(&Ah[buf][lofs + 8]) = h1;
    if (scol == 0) Ce[buf][srow] = pvalid ? (nb2 * sn) : -1e30f;
  };

  // ---- prologue: stage 0 global -> regs -> LDS buf 0 ----
  stage_load(0);
  stage_write(0);
  __syncthreads();

  floatx4 acc0 = {0.f, 0.f, 0.f, 0.f};
  floatx4 acc1 = {0.f, 0.f, 0.f, 0.f};

  for (int st = 0; st < NSTAGE; ++st) {
    const int b = st & 1;

    if (st + 1 < NSTAGE) stage_load(st + 1);

    #pragma unroll
    for (int sub = 0; sub < 4; ++sub) {
      const int abase = (sub * 16 + l15) * LROW + quad * 8;
      const half8 ae0 = *(const half8*)(&Ah[b][abase]);
      const half8 ae1 = *(const half8*)(&Ah[b][abase + 32]);
      const float4 ce4 = *(const float4*)(&Ce[b][sub * 16 + quad * 4]);
      const int4   lb4 = *(const int4*)(&Lb_all[st * SROWS + sub * 16 + quad * 4]);

      floatx4 d0 = {0.f, 0.f, 0.f, 0.f};
      floatx4 d1 = {0.f, 0.f, 0.f, 0.f};
      d0 = __builtin_amdgcn_mfma_f32_16x16x32_f16(ae0, bx00, d0, 0, 0, 0);
      d0 = __builtin_amdgcn_mfma_f32_16x16x32_f16(ae1, bx01, d0, 0, 0, 0);
      d1 = __builtin_amdgcn_mfma_f32_16x16x32_f16(ae0, bx10, d1, 0, 0, 0);
      d1 = __builtin_amdgcn_mfma_f32_16x16x32_f16(ae1, bx11, d1, 0, 0, 0);

      const float cef[4] = { ce4.x, ce4.y, ce4.z, ce4.w };
      float t0[4], t1[4];
      #pragma unroll
      for (int r = 0; r < 4; ++r) {
        t0[r] = fminf(fmaf(s2, d0[r], cb0l + cef[r]), 0.f);  // log2-domain
        t1[r] = fminf(fmaf(s2, d1[r], cb1l + cef[r]), 0.f);
      }

      // dead-subtile skip: t <= -25 => fp16(2^t) == 0 exactly (RTE) => MFMA2
      // is a provable no-op. Wave-uniform branch.
      const float m0 = fmaxf(fmaxf(t0[0], t0[1]), fmaxf(t0[2], t0[3]));
      const float m1 = fmaxf(fmaxf(t1[0], t1[1]), fmaxf(t1[2], t1[3]));
      if (__any(fmaxf(m0, m1) > -25.f)) {
        half4v oh;
        oh[0] = (lb4.x == l15) ? (_Float16)1.f : (_Float16)0.f;
        oh[1] = (lb4.y == l15) ? (_Float16)1.f : (_Float16)0.f;
        oh[2] = (lb4.z == l15) ? (_Float16)1.f : (_Float16)0.f;
        oh[3] = (lb4.w == l15) ? (_Float16)1.f : (_Float16)0.f;

        half4v p0, p1;
        #pragma unroll
        for (int r = 0; r < 4; ++r) {
          p0[r] = (_Float16)exp2_hw(t0[r]);
          p1[r] = (_Float16)exp2_hw(t1[r]);
        }

        acc0 = __builtin_amdgcn_mfma_f32_16x16x16f16(oh, p0, acc0, 0, 0, 0);
        acc1 = __builtin_amdgcn_mfma_f32_16x16x16f16(oh, p1, acc1, 0, 0, 0);
      }
    }

    if (st + 1 < NSTAGE) {
      stage_write((st + 1) & 1);
      __syncthreads();
    }
  }

  // Flush: acc holds class_part[c = quad*4+r][b = l15] per col-group. Private
  // per-chunk slice, plain stores, zero contention (each cell written once).
  float* dst = part + (size_t)chunk * (NB * NC);
  #pragma unroll
  for (int r = 0; r < 4; ++r) {
    const int c = quad * 4 + r;
    if (c < NC) {
      dst[(bm0 + l15) * NC + c] = acc0[r];
      dst[(bm1 + l15) * NC + c] = acc1[r];
    }
  }
}

// ---------------------------------------------------------------------------
// reduce+finalize: out[bc] = log( sum_k part[k][bc] + eps ). Thread bc reads
// part[k][bc] -- consecutive threads hit consecutive addresses (coalesced);
// ~4 MB total, L2/L3-hot. Fixed summation order -> deterministic.
// ---------------------------------------------------------------------------
__global__ __launch_bounds__(256) void reduce_kernel(
    const float* __restrict__ part, float* __restrict__ out)
{
  const int bc = blockIdx.x * 256 + threadIdx.x;
  if (bc < NB * NC) {
    float s = 0.f;
    #pragma unroll 7
    for (int k = 0; k < NCHUNK; ++k) s += part[(size_t)k * (NB * NC) + bc];
    out[bc] = __logf(s + 1e-12f);
  }
}

extern "C" void kernel_launch(void* const* d_in, const int* in_sizes, int n_in,
                              void* d_out, int out_size, void* d_ws, size_t ws_size,
                              hipStream_t stream)
{
  const float* x        = (const float*)d_in[0];
  const float* ex       = (const float*)d_in[1];
  const int*   labels   = (const int*)d_in[2];
  const float* beta_raw = (const float*)d_in[3];
  float* out = (float*)d_out;

  // Workspace: only the contention-free partial array (98*10240*4 = 4,014,080 B)
  float* part = (float*)d_ws;

  dim3 g(NB / BCOLS, NCHUNK);
  main_kernel<<<g, 256, 0, stream>>>(x, ex, labels, beta_raw, part);
  reduce_kernel<<<40, 256, 0, stream>>>(part, out);
}